// Round 9
// baseline (1549.181 us; speedup 1.0000x reference)
//
#include <hip/hip_runtime.h>
#include <hip/hip_bf16.h>

#define NROWS 16384
#define DIM   1024
#define NT    8                          // K-tiles (1024/128)
#define NTILE 64                         // 256-row tiles per dim
#define NBLK  (NTILE * (NTILE + 1) / 2)  // 2080 upper-tri blocks (2080 = 8*260)

typedef int   i32x4 __attribute__((ext_vector_type(4)));
typedef int   i32x8 __attribute__((ext_vector_type(8)));
typedef float f32x4 __attribute__((ext_vector_type(4)));

// monotone float -> uint key (order-preserving), so atomicMax works on floats
__device__ __forceinline__ unsigned fkey(float f) {
    unsigned u = __float_as_uint(f);
    return (u & 0x80000000u) ? ~u : (u | 0x80000000u);
}
__device__ __forceinline__ float funkey(unsigned k) {
    unsigned u = (k & 0x80000000u) ? (k & 0x7fffffffu) : ~k;
    return __uint_as_float(u);
}

// One block per row: fp32 sum-of-squares, scale, emit packed fp8 e4m3 row.
__global__ void normalize_rows(const float* __restrict__ x,
                               unsigned char* __restrict__ xq,
                               unsigned* __restrict__ rowmax) {
    const int row = blockIdx.x;
    const int t = threadIdx.x;                      // 256 threads, 1 float4 each
    const float4 v = ((const float4*)(x + (size_t)row * DIM))[t];
    float ss = v.x * v.x + v.y * v.y + v.z * v.z + v.w * v.w;
#pragma unroll
    for (int off = 32; off > 0; off >>= 1) ss += __shfl_xor(ss, off);
    __shared__ float wss[4];
    if ((t & 63) == 0) wss[t >> 6] = ss;
    __syncthreads();
    const float tot = wss[0] + wss[1] + wss[2] + wss[3];
    const float scale = 1.0f / fmaxf(sqrtf(tot), 1e-12f);
    // pack 4 fp8 bytes: elems k..k+3 -> bytes 0..3 (HW cvt, RNE, OCP e4m3fn)
    int p = 0;
    p = __builtin_amdgcn_cvt_pk_fp8_f32(v.x * scale, v.y * scale, p, false);
    p = __builtin_amdgcn_cvt_pk_fp8_f32(v.z * scale, v.w * scale, p, true);
    ((int*)(xq + (size_t)row * DIM))[t] = p;
    if (t == 0) rowmax[row] = 0u;
}

// ---- simmax, MX-fp8 (e4m3, scale=1.0): R4 skeleton, K-tile = 128 ----
// LDS geometry identical to the bf16 R4 kernel: [buf][A0,A1,B0,B1][128 rows
// x 128 B], XOR-swizzled chunks of 16 B; fp8 halves bytes/elem so K doubles.
// Per wave per K-tile: 24 unique ds_read_b128, 32 mfma_scale_16x16x128,
// 8 staged gload_lds; one vmcnt(0)+raw-barrier at tile top; spread stages;
// setprio around MFMA clusters (the R4-measured-best interleave).

__device__ __forceinline__ void stage_half(const unsigned char* src, char* dstbase, int wid) {
#pragma unroll
    for (int j = 0; j < 2; ++j) {
        __builtin_amdgcn_global_load_lds(
            (const __attribute__((address_space(1))) void*)(src + (size_t)j * 64 * DIM),
            (__attribute__((address_space(3))) void*)(dstbase + (j * 512 + wid * 64) * 16),
            16, 0, 0);
    }
}

template<int H>
__device__ __forceinline__ void read_A(const char* bufb, int wr, int l15, int hq,
                                       i32x8 af[4]) {
#pragma unroll
    for (int m2 = 0; m2 < 4; ++m2) {
        const int rih = wr * 64 + m2 * 16 + l15;
        const int c0  = (2 * hq + 0) ^ (rih & 7);
        const int c1  = (2 * hq + 1) ^ (rih & 7);
        const i32x4 lo = *(const i32x4*)(bufb + H * 16384 + rih * 128 + c0 * 16);
        const i32x4 hi = *(const i32x4*)(bufb + H * 16384 + rih * 128 + c1 * 16);
        af[m2] = __builtin_shufflevector(lo, hi, 0, 1, 2, 3, 4, 5, 6, 7);
    }
}

template<int H>
__device__ __forceinline__ void read_B(const char* bufb, int wc, int l15, int hq,
                                       i32x8 bfr[2]) {
#pragma unroll
    for (int n2 = 0; n2 < 2; ++n2) {
        const int rih = wc * 32 + n2 * 16 + l15;
        const int c0  = (2 * hq + 0) ^ (rih & 7);
        const int c1  = (2 * hq + 1) ^ (rih & 7);
        const i32x4 lo = *(const i32x4*)(bufb + 32768 + H * 16384 + rih * 128 + c0 * 16);
        const i32x4 hi = *(const i32x4*)(bufb + 32768 + H * 16384 + rih * 128 + c1 * 16);
        bfr[n2] = __builtin_shufflevector(lo, hi, 0, 1, 2, 3, 4, 5, 6, 7);
    }
}

template<int QM, int QN>
__device__ __forceinline__ void mfma8(f32x4 acc[8][4], i32x8 af[4], i32x8 bfr[2]) {
#pragma unroll
    for (int m2 = 0; m2 < 4; ++m2)
#pragma unroll
        for (int n2 = 0; n2 < 2; ++n2)
            acc[QM * 4 + m2][QN * 2 + n2] =
                __builtin_amdgcn_mfma_scale_f32_16x16x128_f8f6f4(
                    af[m2], bfr[n2], acc[QM * 4 + m2][QN * 2 + n2],
                    0, 0,            // cbsz = fp8(e4m3) A, blgp = fp8(e4m3) B
                    0, 0x7f,         // scale A: opsel byte0, e8m0 127 = 1.0
                    0, 0x7f);        // scale B
}

#define SB() __builtin_amdgcn_sched_barrier(0)

__global__ __launch_bounds__(512, 2)
void simmax_kernel(const unsigned char* __restrict__ xq,
                   unsigned* __restrict__ rowmax) {
    // T1: bijective XCD-chunked swizzle (2080 = 8 * 260)
    const int bid = blockIdx.x;
    int rem = (bid & 7) * (NBLK / 8) + (bid >> 3);
    int it = 0;
    while (rem >= NTILE - it) { rem -= NTILE - it; ++it; }
    const int jt = it + rem;
    const bool diag = (jt == it);
    const int rowBase = it * 256;
    const int colBase = jt * 256;

    __shared__ __align__(16) char ldsraw[2][4][16384];  // [buf][A0,A1,B0,B1] 128 KiB

    const int t    = threadIdx.x;
    const int lane = t & 63;
    const int wid  = t >> 6;
    const int wr   = wid >> 2;      // 0..1 (M)
    const int wc   = wid & 3;       // 0..3 (N)
    const int l15  = lane & 15;
    const int hq   = lane >> 4;     // 0..3 -> k = hq*32 per fragment

    // staging source: row = halfbase + j*64 + (t>>3), 16-B chunk pre-swizzled
    // (ch ^ (row&7)) so the swizzled ds_read finds its data; LDS dest linear.
    const int rowoff = t >> 3;
    const int scol   = ((t & 7) ^ ((t >> 3) & 7)) * 16;   // bytes
    const unsigned char* srcp[4];
    srcp[0] = xq + (size_t)(rowBase +       rowoff) * DIM + scol;   // A0
    srcp[1] = xq + (size_t)(rowBase + 128 + rowoff) * DIM + scol;   // A1
    srcp[2] = xq + (size_t)(colBase +       rowoff) * DIM + scol;   // B0
    srcp[3] = xq + (size_t)(colBase + 128 + rowoff) * DIM + scol;   // B1

    // prologue: stage K-tile 0 into buf 0
#pragma unroll
    for (int h = 0; h < 4; ++h) {
        stage_half(srcp[h], &ldsraw[0][h][0], wid);
        srcp[h] += 128;
    }

    f32x4 acc[8][4];
#pragma unroll
    for (int m = 0; m < 8; ++m)
#pragma unroll
        for (int n = 0; n < 4; ++n)
            acc[m][n] = (f32x4){0.f, 0.f, 0.f, 0.f};

    for (int tk = 0; tk < NT; ++tk) {
        char* curb = &ldsraw[tk & 1][0][0];
        char* nxtb = &ldsraw[(tk & 1) ^ 1][0][0];
        const bool pf = (tk + 1 < NT);

        // tile top: all stages for THIS tile drained, everyone past epilogue
        asm volatile("s_waitcnt vmcnt(0)" ::: "memory");
        __builtin_amdgcn_s_barrier();
        SB();

        i32x8 af[4], b0[2], b1[2];
        read_A<0>(curb, wr, l15, hq, af);
        read_B<0>(curb, wc, l15, hq, b0);
        read_B<1>(curb, wc, l15, hq, b1);
        SB();
        if (pf) {
            stage_half(srcp[0], nxtb + 0 * 16384, wid); srcp[0] += 128;
            stage_half(srcp[2], nxtb + 2 * 16384, wid); srcp[2] += 128;
        }
        SB();
        __builtin_amdgcn_s_setprio(1);
        mfma8<0, 0>(acc, af, b0);
        __builtin_amdgcn_s_setprio(0);
        SB();
        if (pf) { stage_half(srcp[3], nxtb + 3 * 16384, wid); srcp[3] += 128; }
        SB();
        __builtin_amdgcn_s_setprio(1);
        mfma8<0, 1>(acc, af, b1);
        __builtin_amdgcn_s_setprio(0);
        SB();
        read_A<1>(curb, wr, l15, hq, af);   // af reuse: half-0 frags dead
        SB();
        if (pf) { stage_half(srcp[1], nxtb + 1 * 16384, wid); srcp[1] += 128; }
        SB();
        __builtin_amdgcn_s_setprio(1);
        mfma8<1, 1>(acc, af, b1);
        mfma8<1, 0>(acc, af, b0);
        __builtin_amdgcn_s_setprio(0);
        SB();
    }

    // ---- epilogue: tile max reduction ----
    // acc[qm*4+m2][qn*2+n2]; row = qm*128 + wr*64 + m2*16 + g*4 + r,
    // col = qn*128 + wc*32 + n2*16 + cl  (C/D layout shape-determined, m121-128)
    const int g  = lane >> 4;
    const int cl = lane & 15;

    if (diag) {
#pragma unroll
        for (int qm = 0; qm < 2; ++qm)
#pragma unroll
            for (int m2 = 0; m2 < 4; ++m2)
#pragma unroll
                for (int qn = 0; qn < 2; ++qn)
#pragma unroll
                    for (int n2 = 0; n2 < 2; ++n2)
#pragma unroll
                        for (int r = 0; r < 4; ++r) {
                            const int grow = qm * 128 + wr * 64 + m2 * 16 + g * 4 + r;
                            const int gcol = qn * 128 + wc * 32 + n2 * 16 + cl;
                            if (grow == gcol) acc[qm * 4 + m2][qn * 2 + n2][r] = -3.0f;
                        }
    }

    // row-direction max
#pragma unroll
    for (int qm = 0; qm < 2; ++qm)
#pragma unroll
        for (int m2 = 0; m2 < 4; ++m2)
#pragma unroll
            for (int r = 0; r < 4; ++r) {
                const int am = qm * 4 + m2;
                float v = fmaxf(fmaxf(acc[am][0][r], acc[am][1][r]),
                                fmaxf(acc[am][2][r], acc[am][3][r]));
                v = fmaxf(v, __shfl_xor(v, 1));
                v = fmaxf(v, __shfl_xor(v, 2));
                v = fmaxf(v, __shfl_xor(v, 4));
                v = fmaxf(v, __shfl_xor(v, 8));
                if (cl == 0) {
                    const int grow = rowBase + qm * 128 + wr * 64 + m2 * 16 + g * 4 + r;
                    atomicMax(rowmax + grow, fkey(v));
                }
            }

    // col-direction max (transpose contribution), skip on diagonal tiles
    if (!diag) {
#pragma unroll
        for (int qn = 0; qn < 2; ++qn)
#pragma unroll
            for (int n2 = 0; n2 < 2; ++n2) {
                const int an = qn * 2 + n2;
                float v = -3.0f;
#pragma unroll
                for (int m = 0; m < 8; ++m)
#pragma unroll
                    for (int r = 0; r < 4; ++r)
                        v = fmaxf(v, acc[m][an][r]);
                v = fmaxf(v, __shfl_xor(v, 16));
                v = fmaxf(v, __shfl_xor(v, 32));
                if (g == 0) {
                    const int gcol = colBase + qn * 128 + wc * 32 + n2 * 16 + cl;
                    atomicMax(rowmax + gcol, fkey(v));
                }
            }
    }
}

__global__ void finalize_kernel(const unsigned* __restrict__ rowmax,
                                float* __restrict__ out) {
    const int t = threadIdx.x;
    float s = 0.f;
    for (int r = t; r < NROWS; r += 256) {
        const float m = fminf(funkey(rowmax[r]), 1.0f);   // NaN guard
        s += logf(2.0f - 2.0f * m + 1e-8f);
    }
#pragma unroll
    for (int off = 32; off > 0; off >>= 1) s += __shfl_xor(s, off);
    __shared__ float ws[4];
    if ((t & 63) == 0) ws[t >> 6] = s;
    __syncthreads();
    if (t == 0) out[0] = -0.5f * (ws[0] + ws[1] + ws[2] + ws[3]) / (float)NROWS;
}

extern "C" void kernel_launch(void* const* d_in, const int* in_sizes, int n_in,
                              void* d_out, int out_size, void* d_ws, size_t ws_size,
                              hipStream_t stream) {
    const float* x = (const float*)d_in[0];
    unsigned char* xq = (unsigned char*)d_ws;                       // fp8, 16 MB
    unsigned* rowmax = (unsigned*)((char*)d_ws + (size_t)NROWS * DIM);
    float* out = (float*)d_out;

    normalize_rows<<<NROWS, 256, 0, stream>>>(x, xq, rowmax);
    simmax_kernel<<<NBLK, 512, 0, stream>>>(xq, rowmax);
    finalize_kernel<<<1, 256, 0, stream>>>(rowmax, out);
}

// Round 10
// 408.434 us; speedup vs baseline: 3.7930x; 3.7930x over previous
//
#include <hip/hip_runtime.h>
#include <hip/hip_bf16.h>

#define NROWS 16384
#define DIM   1024
#define NT    16                         // K-tiles (1024/64)
#define NTILE 64                         // 256-row tiles per dim
#define NBLK  (NTILE * (NTILE + 1) / 2)  // 2080 upper-tri blocks (2080 = 8*260)

typedef __bf16 bf16x8 __attribute__((ext_vector_type(8)));
typedef __bf16 bf16x4 __attribute__((ext_vector_type(4)));
typedef float  f32x4  __attribute__((ext_vector_type(4)));

// monotone float -> uint key (order-preserving), so atomicMax works on floats
__device__ __forceinline__ unsigned fkey(float f) {
    unsigned u = __float_as_uint(f);
    return (u & 0x80000000u) ? ~u : (u | 0x80000000u);
}
__device__ __forceinline__ float funkey(unsigned k) {
    unsigned u = (k & 0x80000000u) ? (k & 0x7fffffffu) : ~k;
    return __uint_as_float(u);
}

__global__ void normalize_rows(const float* __restrict__ x,
                               __hip_bfloat16* __restrict__ xn,
                               unsigned* __restrict__ rowmax) {
    const int row = blockIdx.x;
    const int t = threadIdx.x;                      // 256 threads, 1 float4 each
    const float4 v = ((const float4*)(x + (size_t)row * DIM))[t];
    float ss = v.x * v.x + v.y * v.y + v.z * v.z + v.w * v.w;
#pragma unroll
    for (int off = 32; off > 0; off >>= 1) ss += __shfl_xor(ss, off);
    __shared__ float wss[4];
    if ((t & 63) == 0) wss[t >> 6] = ss;
    __syncthreads();
    const float tot = wss[0] + wss[1] + wss[2] + wss[3];
    const float scale = 1.0f / fmaxf(sqrtf(tot), 1e-12f);
    bf16x4 o;
    o[0] = (__bf16)(v.x * scale);
    o[1] = (__bf16)(v.y * scale);
    o[2] = (__bf16)(v.z * scale);
    o[3] = (__bf16)(v.w * scale);
    *(bf16x4*)(xn + (size_t)row * DIM + t * 4) = o;
    if (t == 0) rowmax[row] = 0u;
}

// ---- simmax: m201-template 4-phase pipeline with VERIFIED counted-wait
// ledger. LDS [buf][A0,A1,B0,B1][16KB] dbuf. Per tile t:
//  phi1: read A0(8)+B0(4); stage A0'; lgkmcnt(8); vmcnt(4); BAR; lgkm0; MFMA(0,0); BAR
//  phi2: read B1(4);       stage B0'; vmcnt(4);              BAR; lgkm0; MFMA(0,1); BAR
//  phi3: read A1(8) [af reuse]; stage B1';                   BAR; lgkm0; MFMA(1,1); BAR
//  phi4: (no reads);       stage A1'; vmcnt(4|0 tail);       BAR;        MFMA(1,0); BAR
// Ledger (steady, simulated): entering tile t in-flight = {B1_t,A1_t};
// phi1's vmcnt(4) drains B1_t (needed phi2), phi2's drains A1_t (needed
// phi3), phi4's drains A0_{t+1},B0_{t+1} (needed next phi1). All drained
// loads are 2-3 phases (~500-750cy) old; never drains to 0 except once at
// tile NT-2. Every wait precedes a barrier, every dependent read is >=1
// barrier later => race-free across waves. No sched_barrier(0) fences.

__device__ __forceinline__ void stage_half(const __hip_bfloat16* src, char* dstbase, int wid) {
#pragma unroll
    for (int j = 0; j < 2; ++j) {
        __builtin_amdgcn_global_load_lds(
            (const __attribute__((address_space(1))) void*)(src + (size_t)j * 64 * DIM),
            (__attribute__((address_space(3))) void*)(dstbase + (j * 512 + wid * 64) * 16),
            16, 0, 0);
    }
}

template<int QM>
__device__ __forceinline__ void read_A(const char* bufb, int wr, int l15, int hi,
                                       bf16x8 af[4][2]) {
#pragma unroll
    for (int m2 = 0; m2 < 4; ++m2)
#pragma unroll
        for (int kk = 0; kk < 2; ++kk) {
            const int rih = wr * 64 + m2 * 16 + l15;
            const int chn = (kk * 4 + hi) ^ (rih & 7);
            af[m2][kk] = *(const bf16x8*)(bufb + QM * 16384 + rih * 128 + chn * 16);
        }
}

template<int QN>
__device__ __forceinline__ void read_B(const char* bufb, int wc, int l15, int hi,
                                       bf16x8 bfr[2][2]) {
#pragma unroll
    for (int n2 = 0; n2 < 2; ++n2)
#pragma unroll
        for (int kk = 0; kk < 2; ++kk) {
            const int rih = wc * 32 + n2 * 16 + l15;
            const int chn = (kk * 4 + hi) ^ (rih & 7);
            bfr[n2][kk] = *(const bf16x8*)(bufb + 32768 + QN * 16384 + rih * 128 + chn * 16);
        }
}

template<int QM, int QN>
__device__ __forceinline__ void mfma16(f32x4 acc[8][4], bf16x8 af[4][2], bf16x8 bfr[2][2]) {
#pragma unroll
    for (int m2 = 0; m2 < 4; ++m2)
#pragma unroll
        for (int n2 = 0; n2 < 2; ++n2)
#pragma unroll
            for (int kk = 0; kk < 2; ++kk)
                acc[QM * 4 + m2][QN * 2 + n2] = __builtin_amdgcn_mfma_f32_16x16x32_bf16(
                    af[m2][kk], bfr[n2][kk], acc[QM * 4 + m2][QN * 2 + n2], 0, 0, 0);
}

__global__ __launch_bounds__(512, 2)
void simmax_kernel(const __hip_bfloat16* __restrict__ xn,
                   unsigned* __restrict__ rowmax) {
    // T1: bijective XCD-chunked swizzle (2080 = 8 * 260)
    const int bid = blockIdx.x;
    int rem = (bid & 7) * (NBLK / 8) + (bid >> 3);
    int it = 0;
    while (rem >= NTILE - it) { rem -= NTILE - it; ++it; }
    const int jt = it + rem;
    const bool diag = (jt == it);
    const int rowBase = it * 256;
    const int colBase = jt * 256;

    __shared__ __align__(16) char ldsraw[2][4][16384];  // [buf][A0,A1,B0,B1] 128 KiB

    const int t    = threadIdx.x;
    const int lane = t & 63;
    const int wid  = t >> 6;
    const int wr   = wid >> 2;      // 0..1 (M)
    const int wc   = wid & 3;      // 0..3 (N)
    const int l15  = lane & 15;
    const int hi   = lane >> 4;

    // staging source: row = halfbase + j*64 + (t>>3), col pre-swizzled so the
    // swizzled ds_read finds its data; LDS dest stays linear (rule #21)
    const int rowoff = t >> 3;
    const int scol   = ((t & 7) ^ ((t >> 3) & 7)) * 8;
    const __hip_bfloat16* srcp[4];
    srcp[0] = xn + (size_t)(rowBase +       rowoff) * DIM + scol;   // A0 -> half 0
    srcp[1] = xn + (size_t)(rowBase + 128 + rowoff) * DIM + scol;   // A1 -> half 1
    srcp[2] = xn + (size_t)(colBase +       rowoff) * DIM + scol;   // B0 -> half 2
    srcp[3] = xn + (size_t)(colBase + 128 + rowoff) * DIM + scol;   // B1 -> half 3

    // prologue: stage tile 0 (issue order A0,B0,B1,A1), vmcnt(4) leaves
    // {B1_0,A1_0} in flight -> steady-state invariant holds at tile 0 entry
    stage_half(srcp[0], &ldsraw[0][0][0], wid); srcp[0] += 64;
    stage_half(srcp[2], &ldsraw[0][2][0], wid); srcp[2] += 64;
    stage_half(srcp[3], &ldsraw[0][3][0], wid); srcp[3] += 64;
    stage_half(srcp[1], &ldsraw[0][1][0], wid); srcp[1] += 64;
    asm volatile("s_waitcnt vmcnt(4)" ::: "memory");
    __builtin_amdgcn_s_barrier();

    f32x4 acc[8][4];
#pragma unroll
    for (int m = 0; m < 8; ++m)
#pragma unroll
        for (int n = 0; n < 4; ++n)
            acc[m][n] = (f32x4){0.f, 0.f, 0.f, 0.f};

    for (int tk = 0; tk < NT; ++tk) {
        char* curb = &ldsraw[tk & 1][0][0];
        char* nxtb = &ldsraw[(tk & 1) ^ 1][0][0];
        const bool pf  = (tk + 1 < NT);
        const bool pf2 = (tk + 2 < NT);

        bf16x8 af[4][2], b0[2][2], b1[2][2];

        // ---- phi1 ----
        read_A<0>(curb, wr, l15, hi, af);
        read_B<0>(curb, wc, l15, hi, b0);
        if (pf) { stage_half(srcp[0], nxtb + 0 * 16384, wid); srcp[0] += 64; }
        asm volatile("s_waitcnt lgkmcnt(8)" ::: "memory");
        if (pf) asm volatile("s_waitcnt vmcnt(4)" ::: "memory");
        __builtin_amdgcn_s_barrier();
        asm volatile("s_waitcnt lgkmcnt(0)" ::: "memory");
        __builtin_amdgcn_s_setprio(1);
        mfma16<0, 0>(acc, af, b0);
        __builtin_amdgcn_s_setprio(0);
        __builtin_amdgcn_s_barrier();

        // ---- phi2 ----
        read_B<1>(curb, wc, l15, hi, b1);
        if (pf) { stage_half(srcp[2], nxtb + 2 * 16384, wid); srcp[2] += 64; }
        if (pf) asm volatile("s_waitcnt vmcnt(4)" ::: "memory");
        __builtin_amdgcn_s_barrier();
        asm volatile("s_waitcnt lgkmcnt(0)" ::: "memory");
        __builtin_amdgcn_s_setprio(1);
        mfma16<0, 1>(acc, af, b1);
        __builtin_amdgcn_s_setprio(0);
        __builtin_amdgcn_s_barrier();

        // ---- phi3 ----
        read_A<1>(curb, wr, l15, hi, af);   // af reuse: half-0 frags dead
        if (pf) { stage_half(srcp[3], nxtb + 3 * 16384, wid); srcp[3] += 64; }
        __builtin_amdgcn_s_barrier();
        asm volatile("s_waitcnt lgkmcnt(0)" ::: "memory");
        __builtin_amdgcn_s_setprio(1);
        mfma16<1, 1>(acc, af, b1);
        __builtin_amdgcn_s_setprio(0);
        __builtin_amdgcn_s_barrier();

        // ---- phi4 ----
        if (pf) { stage_half(srcp[1], nxtb + 1 * 16384, wid); srcp[1] += 64; }
        if (pf2)     asm volatile("s_waitcnt vmcnt(4)" ::: "memory");
        else if (pf) asm volatile("s_waitcnt vmcnt(0)" ::: "memory");
        __builtin_amdgcn_s_barrier();
        __builtin_amdgcn_s_setprio(1);
        mfma16<1, 0>(acc, af, b0);
        __builtin_amdgcn_s_setprio(0);
        __builtin_amdgcn_s_barrier();
    }

    // ---- epilogue: tile max reduction ----
    // acc[qm*4+m2][qn*2+n2]; row = qm*128 + wr*64 + m2*16 + g*4 + r,
    // col = qn*128 + wc*32 + n2*16 + cl  (C/D layout m89/m91)
    const int g  = lane >> 4;
    const int cl = lane & 15;

    if (diag) {
#pragma unroll
        for (int qm = 0; qm < 2; ++qm)
#pragma unroll
            for (int m2 = 0; m2 < 4; ++m2)
#pragma unroll
                for (int qn = 0; qn < 2; ++qn)
#pragma unroll
                    for (int n2 = 0; n2 < 2; ++n2)
#pragma unroll
                        for (int r = 0; r < 4; ++r) {
                            const int grow = qm * 128 + wr * 64 + m2 * 16 + g * 4 + r;
                            const int gcol = qn * 128 + wc * 32 + n2 * 16 + cl;
                            if (grow == gcol) acc[qm * 4 + m2][qn * 2 + n2][r] = -3.0f;
                        }
    }

    // row-direction max
#pragma unroll
    for (int qm = 0; qm < 2; ++qm)
#pragma unroll
        for (int m2 = 0; m2 < 4; ++m2)
#pragma unroll
            for (int r = 0; r < 4; ++r) {
                const int am = qm * 4 + m2;
                float v = fmaxf(fmaxf(acc[am][0][r], acc[am][1][r]),
                                fmaxf(acc[am][2][r], acc[am][3][r]));
                v = fmaxf(v, __shfl_xor(v, 1));
                v = fmaxf(v, __shfl_xor(v, 2));
                v = fmaxf(v, __shfl_xor(v, 4));
                v = fmaxf(v, __shfl_xor(v, 8));
                if (cl == 0) {
                    const int grow = rowBase + qm * 128 + wr * 64 + m2 * 16 + g * 4 + r;
                    atomicMax(rowmax + grow, fkey(v));
                }
            }

    // col-direction max (transpose contribution), skip on diagonal tiles
    if (!diag) {
#pragma unroll
        for (int qn = 0; qn < 2; ++qn)
#pragma unroll
            for (int n2 = 0; n2 < 2; ++n2) {
                const int an = qn * 2 + n2;
                float v = -3.0f;
#pragma unroll
                for (int m = 0; m < 8; ++m)
#pragma unroll
                    for (int r = 0; r < 4; ++r)
                        v = fmaxf(v, acc[m][an][r]);
                v = fmaxf(v, __shfl_xor(v, 16));
                v = fmaxf(v, __shfl_xor(v, 32));
                if (g == 0) {
                    const int gcol = colBase + qn * 128 + wc * 32 + n2 * 16 + cl;
                    atomicMax(rowmax + gcol, fkey(v));
                }
            }
    }
}

__global__ void finalize_kernel(const unsigned* __restrict__ rowmax,
                                float* __restrict__ out) {
    const int t = threadIdx.x;
    float s = 0.f;
    for (int r = t; r < NROWS; r += 256) {
        const float m = fminf(funkey(rowmax[r]), 1.0f);   // NaN guard
        s += logf(2.0f - 2.0f * m + 1e-8f);
    }
#pragma unroll
    for (int off = 32; off > 0; off >>= 1) s += __shfl_xor(s, off);
    __shared__ float ws[4];
    if ((t & 63) == 0) ws[t >> 6] = s;
    __syncthreads();
    if (t == 0) out[0] = -0.5f * (ws[0] + ws[1] + ws[2] + ws[3]) / (float)NROWS;
}

extern "C" void kernel_launch(void* const* d_in, const int* in_sizes, int n_in,
                              void* d_out, int out_size, void* d_ws, size_t ws_size,
                              hipStream_t stream) {
    const float* x = (const float*)d_in[0];
    __hip_bfloat16* xn = (__hip_bfloat16*)d_ws;
    unsigned* rowmax = (unsigned*)((char*)d_ws + (size_t)NROWS * DIM * sizeof(__hip_bfloat16));
    float* out = (float*)d_out;

    normalize_rows<<<NROWS, 256, 0, stream>>>(x, xn, rowmax);
    simmax_kernel<<<NBLK, 512, 0, stream>>>(xn, rowmax);
    finalize_kernel<<<1, 256, 0, stream>>>(rowmax, out);
}

// Round 11
// 399.895 us; speedup vs baseline: 3.8740x; 1.0214x over previous
//
#include <hip/hip_runtime.h>
#include <hip/hip_bf16.h>

#define NROWS 16384
#define DIM   1024
#define NT    16                         // K-tiles (1024/64)
#define NTILE 128                        // 128-row tiles per dim
#define NBLK  (NTILE * (NTILE + 1) / 2)  // 8256 upper-tri blocks (= 8*1032)

typedef __bf16 bf16x8 __attribute__((ext_vector_type(8)));
typedef __bf16 bf16x4 __attribute__((ext_vector_type(4)));
typedef float  f32x4  __attribute__((ext_vector_type(4)));

// monotone float -> uint key (order-preserving), so atomicMax works on floats
__device__ __forceinline__ unsigned fkey(float f) {
    unsigned u = __float_as_uint(f);
    return (u & 0x80000000u) ? ~u : (u | 0x80000000u);
}
__device__ __forceinline__ float funkey(unsigned k) {
    unsigned u = (k & 0x80000000u) ? (k & 0x7fffffffu) : ~k;
    return __uint_as_float(u);
}

__global__ void normalize_rows(const float* __restrict__ x,
                               __hip_bfloat16* __restrict__ xn,
                               unsigned* __restrict__ rowmax) {
    const int row = blockIdx.x;
    const int t = threadIdx.x;                      // 256 threads, 1 float4 each
    const float4 v = ((const float4*)(x + (size_t)row * DIM))[t];
    float ss = v.x * v.x + v.y * v.y + v.z * v.z + v.w * v.w;
#pragma unroll
    for (int off = 32; off > 0; off >>= 1) ss += __shfl_xor(ss, off);
    __shared__ float wss[4];
    if ((t & 63) == 0) wss[t >> 6] = ss;
    __syncthreads();
    const float tot = wss[0] + wss[1] + wss[2] + wss[3];
    const float scale = 1.0f / fmaxf(sqrtf(tot), 1e-12f);
    bf16x4 o;
    o[0] = (__bf16)(v.x * scale);
    o[1] = (__bf16)(v.y * scale);
    o[2] = (__bf16)(v.z * scale);
    o[3] = (__bf16)(v.w * scale);
    *(bf16x4*)(xn + (size_t)row * DIM + t * 4) = o;
    if (t == 0) rowmax[row] = 0u;
}

// ---- simmax: faithful m97 structure on the triangle ----
// 128x128 tile, BK=64, 256 threads (2x2 waves, 64x64 out/wave), SINGLE
// 32 KiB LDS buffer, plain 2-barrier K-loop (no asm waits; the compiler's
// counted lgkmcnt does fine LDS->MFMA scheduling; __syncthreads' vmcnt(0)
// drain is covered by ~3 blocks/CU cross-block overlap -- the m97/m114
// mechanism that our 1-block/CU 256-tile kernels lacked). XOR-swizzled
// chunks (pre-swizzled global source, linear gload_lds dest, swizzled
// ds_read) keep bank conflicts at 0.

__global__ __launch_bounds__(256, 3)
void simmax_kernel(const __hip_bfloat16* __restrict__ xn,
                   unsigned* __restrict__ rowmax) {
    // T1: bijective XCD-chunked swizzle (8256 = 8 * 1032)
    const int bid = blockIdx.x;
    int rem = (bid & 7) * (NBLK / 8) + (bid >> 3);
    int it = 0;
    while (rem >= NTILE - it) { rem -= NTILE - it; ++it; }
    const int jt = it + rem;
    const bool diag = (jt == it);
    const int rowBase = it * 128;
    const int colBase = jt * 128;

    __shared__ __align__(16) char lds[2][128][128];  // [A/B][row][64 k * 2B] = 32 KiB

    const int t    = threadIdx.x;                    // 256 = 4 waves
    const int lane = t & 63;
    const int wid  = t >> 6;
    const int wr2  = wid >> 1;     // 0..1 (M)
    const int wc2  = wid & 1;      // 0..1 (N)
    const int l15  = lane & 15;
    const int hi   = lane >> 4;

    // staging: chunk c = j*256 + t (j=0..7); op = c>>10 (A/B); cc = c&1023;
    // row = cc>>3, ch = cc&7. LDS dest LINEAR (c*16 B); SOURCE chunk
    // pre-swizzled (ch ^ (row&7)) so the swizzled ds_read finds it (rule #21).
    const __hip_bfloat16* srcp[8];
#pragma unroll
    for (int j = 0; j < 8; ++j) {
        const int c   = j * 256 + t;
        const int op  = c >> 10;
        const int cc  = c & 1023;
        const int row = cc >> 3;
        const int ch  = cc & 7;
        const int gr  = (op ? colBase : rowBase) + row;
        srcp[j] = xn + (size_t)gr * DIM + (ch ^ (row & 7)) * 8;
    }

    f32x4 acc[4][4];
#pragma unroll
    for (int m = 0; m < 4; ++m)
#pragma unroll
        for (int n = 0; n < 4; ++n)
            acc[m][n] = (f32x4){0.f, 0.f, 0.f, 0.f};

    char* ldsb = &lds[0][0][0];

    for (int kt = 0; kt < NT; ++kt) {
        __syncthreads();               // previous tile's compute done
#pragma unroll
        for (int j = 0; j < 8; ++j) {
            __builtin_amdgcn_global_load_lds(
                (const __attribute__((address_space(1))) void*)srcp[j],
                (__attribute__((address_space(3))) void*)(ldsb + (j * 256 + wid * 64) * 16),
                16, 0, 0);
            srcp[j] += 64;
        }
        __syncthreads();               // drains vmcnt(0): staged data visible

        bf16x8 af[4][2], bf[4][2];
#pragma unroll
        for (int m = 0; m < 4; ++m)
#pragma unroll
            for (int kk = 0; kk < 2; ++kk) {
                const int row = wr2 * 64 + m * 16 + l15;
                const int chn = (kk * 4 + hi) ^ (row & 7);
                af[m][kk] = *(const bf16x8*)(&lds[0][0][0] + row * 128 + chn * 16);
            }
#pragma unroll
        for (int n = 0; n < 4; ++n)
#pragma unroll
            for (int kk = 0; kk < 2; ++kk) {
                const int row = wc2 * 64 + n * 16 + l15;
                const int chn = (kk * 4 + hi) ^ (row & 7);
                bf[n][kk] = *(const bf16x8*)(&lds[1][0][0] + row * 128 + chn * 16);
            }
#pragma unroll
        for (int m = 0; m < 4; ++m)
#pragma unroll
            for (int n = 0; n < 4; ++n)
#pragma unroll
                for (int kk = 0; kk < 2; ++kk)
                    acc[m][n] = __builtin_amdgcn_mfma_f32_16x16x32_bf16(
                        af[m][kk], bf[n][kk], acc[m][n], 0, 0, 0);
    }

    // ---- epilogue: tile max reduction ----
    // C/D layout: col = lane&15, row = (lane>>4)*4 + reg  [m89/m91]
    const int g  = lane >> 4;
    const int cl = lane & 15;

    if (diag) {                        // mask self-similarity
#pragma unroll
        for (int m = 0; m < 4; ++m)
#pragma unroll
            for (int n = 0; n < 4; ++n)
#pragma unroll
                for (int r = 0; r < 4; ++r) {
                    const int grow = wr2 * 64 + m * 16 + g * 4 + r;
                    const int gcol = wc2 * 64 + n * 16 + cl;
                    if (grow == gcol) acc[m][n][r] = -3.0f;
                }
    }

    // row-direction max (over this tile's 128 cols: wave covers 64, pair via n)
#pragma unroll
    for (int m = 0; m < 4; ++m)
#pragma unroll
        for (int r = 0; r < 4; ++r) {
            float v = fmaxf(fmaxf(acc[m][0][r], acc[m][1][r]),
                            fmaxf(acc[m][2][r], acc[m][3][r]));
            v = fmaxf(v, __shfl_xor(v, 1));
            v = fmaxf(v, __shfl_xor(v, 2));
            v = fmaxf(v, __shfl_xor(v, 4));
            v = fmaxf(v, __shfl_xor(v, 8));
            if (cl == 0) {
                const int grow = rowBase + wr2 * 64 + m * 16 + g * 4 + r;
                atomicMax(rowmax + grow, fkey(v));
            }
        }

    // col-direction max (transpose contribution), skip on diagonal tiles
    if (!diag) {
#pragma unroll
        for (int n = 0; n < 4; ++n) {
            float v = -3.0f;
#pragma unroll
            for (int m = 0; m < 4; ++m)
#pragma unroll
                for (int r = 0; r < 4; ++r)
                    v = fmaxf(v, acc[m][n][r]);
            v = fmaxf(v, __shfl_xor(v, 16));
            v = fmaxf(v, __shfl_xor(v, 32));
            if (g == 0) {
                const int gcol = colBase + wc2 * 64 + n * 16 + cl;
                atomicMax(rowmax + gcol, fkey(v));
            }
        }
    }
}

__global__ void finalize_kernel(const unsigned* __restrict__ rowmax,
                                float* __restrict__ out) {
    const int t = threadIdx.x;
    float s = 0.f;
    for (int r = t; r < NROWS; r += 256) {
        const float m = fminf(funkey(rowmax[r]), 1.0f);   // NaN guard
        s += logf(2.0f - 2.0f * m + 1e-8f);
    }
#pragma unroll
    for (int off = 32; off > 0; off >>= 1) s += __shfl_xor(s, off);
    __shared__ float ws[4];
    if ((t & 63) == 0) ws[t >> 6] = s;
    __syncthreads();
    if (t == 0) out[0] = -0.5f * (ws[0] + ws[1] + ws[2] + ws[3]) / (float)NROWS;
}

extern "C" void kernel_launch(void* const* d_in, const int* in_sizes, int n_in,
                              void* d_out, int out_size, void* d_ws, size_t ws_size,
                              hipStream_t stream) {
    const float* x = (const float*)d_in[0];
    __hip_bfloat16* xn = (__hip_bfloat16*)d_ws;
    unsigned* rowmax = (unsigned*)((char*)d_ws + (size_t)NROWS * DIM * sizeof(__hip_bfloat16));
    float* out = (float*)d_out;

    normalize_rows<<<NROWS, 256, 0, stream>>>(x, xn, rowmax);
    simmax_kernel<<<NBLK, 256, 0, stream>>>(xn, rowmax);
    finalize_kernel<<<1, 256, 0, stream>>>(rowmax, out);
}

// Round 12
// 312.402 us; speedup vs baseline: 4.9589x; 1.2801x over previous
//
#include <hip/hip_runtime.h>
#include <hip/hip_bf16.h>

#define NROWS 16384
#define DIM   1024
#define NT    8                          // K-tiles (1024 / 128 i8)
#define NTILE 64                         // 256-row tiles per dim
#define NBLK  (NTILE * (NTILE + 1) / 2)  // 2080 upper-tri blocks (2080 = 8*260)

typedef int i32x4 __attribute__((ext_vector_type(4)));

// monotone float -> uint key (order-preserving), so atomicMax works on floats
__device__ __forceinline__ unsigned fkey(float f) {
    unsigned u = __float_as_uint(f);
    return (u & 0x80000000u) ? ~u : (u | 0x80000000u);
}
__device__ __forceinline__ float funkey(unsigned k) {
    unsigned u = (k & 0x80000000u) ? (k & 0x7fffffffu) : ~k;
    return __uint_as_float(u);
}

// One block per row: fp32 norm, quantize q = round(127*x/||x||) (i8), store
// packed; also per-row inverse quantized norm s = 1/||q|| so sim is the EXACT
// cosine of the integer vectors (removes norm quantization error).
__global__ void normalize_rows(const float* __restrict__ x,
                               signed char* __restrict__ xq,
                               float* __restrict__ sinv,
                               unsigned* __restrict__ rowmax) {
    const int row = blockIdx.x;
    const int t = threadIdx.x;                      // 256 threads, 1 float4 each
    const float4 v = ((const float4*)(x + (size_t)row * DIM))[t];
    float ss = v.x * v.x + v.y * v.y + v.z * v.z + v.w * v.w;
#pragma unroll
    for (int off = 32; off > 0; off >>= 1) ss += __shfl_xor(ss, off);
    __shared__ float wss[4];
    __shared__ int   wqs[4];
    if ((t & 63) == 0) wss[t >> 6] = ss;
    __syncthreads();
    const float tot = wss[0] + wss[1] + wss[2] + wss[3];
    const float scale = 127.0f / fmaxf(sqrtf(tot), 1e-12f);
    int qx = __float2int_rn(v.x * scale);
    int qy = __float2int_rn(v.y * scale);
    int qz = __float2int_rn(v.z * scale);
    int qw = __float2int_rn(v.w * scale);
    qx = max(-127, min(127, qx)); qy = max(-127, min(127, qy));
    qz = max(-127, min(127, qz)); qw = max(-127, min(127, qw));
    const int p = (qx & 0xff) | ((qy & 0xff) << 8) | ((qz & 0xff) << 16) | ((qw & 0xff) << 24);
    ((int*)(xq + (size_t)row * DIM))[t] = p;
    int qs = qx * qx + qy * qy + qz * qz + qw * qw;
#pragma unroll
    for (int off = 32; off > 0; off >>= 1) qs += __shfl_xor(qs, off);
    if ((t & 63) == 0) wqs[t >> 6] = qs;
    __syncthreads();
    if (t == 0) {
        const int qtot = max(wqs[0] + wqs[1] + wqs[2] + wqs[3], 1);
        sinv[row] = 1.0f / sqrtf((float)qtot);
        rowmax[row] = 0u;
    }
}

// ---- simmax, i8: EXACT R4 skeleton (the 355us structure), K-tile = 128 ----
// LDS [buf][A0,A1,B0,B1][128 rows x 128 B] = 128 KiB dbuf -- byte-identical
// geometry to the bf16 R4 kernel (i8 halves bytes/elem so K doubles, NT 16->8:
// every per-tile cost halves). XOR-swizzled 16B chunks (pre-swizzled global
// source, linear gload_lds dest, swizzled ds_read). One vmcnt(0)+raw-barrier
// per tile at tile END; stages spread through the tile; setprio around MFMA
// clusters; SB fences between sections (the R4-measured-best interleave).

__device__ __forceinline__ void stage_half(const signed char* src, char* dstbase, int wid) {
#pragma unroll
    for (int j = 0; j < 2; ++j) {
        __builtin_amdgcn_global_load_lds(
            (const __attribute__((address_space(1))) void*)(src + (size_t)j * 64 * DIM),
            (__attribute__((address_space(3))) void*)(dstbase + (j * 512 + wid * 64) * 16),
            16, 0, 0);
    }
}

template<int H>
__device__ __forceinline__ void read_A(const char* bufb, int wr, int l15, int hi,
                                       i32x4 af[4][2]) {
#pragma unroll
    for (int m2 = 0; m2 < 4; ++m2)
#pragma unroll
        for (int kk = 0; kk < 2; ++kk) {
            const int rih = wr * 64 + m2 * 16 + l15;
            const int chn = (kk * 4 + hi) ^ (rih & 7);
            af[m2][kk] = *(const i32x4*)(bufb + H * 16384 + rih * 128 + chn * 16);
        }
}

template<int H>
__device__ __forceinline__ void read_B(const char* bufb, int wc, int l15, int hi,
                                       i32x4 bfr[2][2]) {
#pragma unroll
    for (int n2 = 0; n2 < 2; ++n2)
#pragma unroll
        for (int kk = 0; kk < 2; ++kk) {
            const int rih = wc * 32 + n2 * 16 + l15;
            const int chn = (kk * 4 + hi) ^ (rih & 7);
            bfr[n2][kk] = *(const i32x4*)(bufb + 32768 + H * 16384 + rih * 128 + chn * 16);
        }
}

template<int QM, int QN>
__device__ __forceinline__ void mfma16(i32x4 acc[8][4], i32x4 af[4][2], i32x4 bfr[2][2]) {
#pragma unroll
    for (int m2 = 0; m2 < 4; ++m2)
#pragma unroll
        for (int n2 = 0; n2 < 2; ++n2)
#pragma unroll
            for (int kk = 0; kk < 2; ++kk)
                acc[QM * 4 + m2][QN * 2 + n2] = __builtin_amdgcn_mfma_i32_16x16x64_i8(
                    af[m2][kk], bfr[n2][kk], acc[QM * 4 + m2][QN * 2 + n2], 0, 0, 0);
}

#define SB() __builtin_amdgcn_sched_barrier(0)

__global__ __launch_bounds__(512, 2)
void simmax_kernel(const signed char* __restrict__ xq,
                   const float* __restrict__ sinv,
                   unsigned* __restrict__ rowmax) {
    // T1: bijective XCD-chunked swizzle (2080 = 8 * 260)
    const int bid = blockIdx.x;
    int rem = (bid & 7) * (NBLK / 8) + (bid >> 3);
    int it = 0;
    while (rem >= NTILE - it) { rem -= NTILE - it; ++it; }
    const int jt = it + rem;
    const bool diag = (jt == it);
    const int rowBase = it * 256;
    const int colBase = jt * 256;

    __shared__ __align__(16) char ldsraw[2][4][16384];  // [buf][A0,A1,B0,B1] 128 KiB

    const int t    = threadIdx.x;
    const int lane = t & 63;
    const int wid  = t >> 6;
    const int wr   = wid >> 2;      // 0..1 (M)
    const int wc   = wid & 3;       // 0..3 (N)
    const int l15  = lane & 15;
    const int hi   = lane >> 4;

    // staging source: row = halfbase + j*64 + (t>>3), 16B chunk pre-swizzled
    // (ch ^ (row&7)) so the swizzled ds_read finds its data; LDS dest linear.
    const int rowoff = t >> 3;
    const int scol   = ((t & 7) ^ ((t >> 3) & 7)) * 16;   // bytes
    const signed char* srcp[4];
    srcp[0] = xq + (size_t)(rowBase +       rowoff) * DIM + scol;   // A0
    srcp[1] = xq + (size_t)(rowBase + 128 + rowoff) * DIM + scol;   // A1
    srcp[2] = xq + (size_t)(colBase +       rowoff) * DIM + scol;   // B0
    srcp[3] = xq + (size_t)(colBase + 128 + rowoff) * DIM + scol;   // B1

    // prologue: stage K-tile 0 into buf 0, drain once
#pragma unroll
    for (int h = 0; h < 4; ++h) {
        stage_half(srcp[h], &ldsraw[0][h][0], wid);
        srcp[h] += 128;
    }
    asm volatile("s_waitcnt vmcnt(0)" ::: "memory");
    __builtin_amdgcn_s_barrier();
    SB();

    i32x4 acc[8][4];
#pragma unroll
    for (int m = 0; m < 8; ++m)
#pragma unroll
        for (int n = 0; n < 4; ++n)
            acc[m][n] = (i32x4){0, 0, 0, 0};

    for (int tk = 0; tk < NT; ++tk) {
        char* curb = &ldsraw[tk & 1][0][0];
        char* nxtb = &ldsraw[(tk & 1) ^ 1][0][0];
        const bool pf = (tk + 1 < NT);

        i32x4 af[4][2], b0[2][2], b1[2][2];

        read_A<0>(curb, wr, l15, hi, af);
        read_B<0>(curb, wc, l15, hi, b0);
        read_B<1>(curb, wc, l15, hi, b1);
        SB();
        if (pf) {
            stage_half(srcp[0], nxtb + 0 * 16384, wid); srcp[0] += 128;
            stage_half(srcp[2], nxtb + 2 * 16384, wid); srcp[2] += 128;
        }
        SB();
        __builtin_amdgcn_s_setprio(1);
        mfma16<0, 0>(acc, af, b0);
        __builtin_amdgcn_s_setprio(0);
        SB();
        if (pf) { stage_half(srcp[3], nxtb + 3 * 16384, wid); srcp[3] += 128; }
        SB();
        __builtin_amdgcn_s_setprio(1);
        mfma16<0, 1>(acc, af, b1);
        __builtin_amdgcn_s_setprio(0);
        SB();
        read_A<1>(curb, wr, l15, hi, af);   // af reuse: half-0 frags dead
        SB();
        if (pf) { stage_half(srcp[1], nxtb + 1 * 16384, wid); srcp[1] += 128; }
        SB();
        __builtin_amdgcn_s_setprio(1);
        mfma16<1, 1>(acc, af, b1);
        mfma16<1, 0>(acc, af, b0);
        __builtin_amdgcn_s_setprio(0);
        SB();

        asm volatile("s_waitcnt vmcnt(0)" ::: "memory");
        __builtin_amdgcn_s_barrier();
        SB();
    }

    // ---- epilogue: scaled tile max reduction ----
    // acc[qm*4+m2][qn*2+n2]; row = qm*128 + wr*64 + m2*16 + g*4 + r,
    // col = qn*128 + wc*32 + n2*16 + cl  (C/D layout shape-determined)
    const int g  = lane >> 4;
    const int cl = lane & 15;

    // column scales (this lane's 4 columns) and row scales (this lane's 32 rows)
    float scl_col[4];
#pragma unroll
    for (int an = 0; an < 4; ++an)
        scl_col[an] = sinv[colBase + (an >> 1) * 128 + wc * 32 + (an & 1) * 16 + cl];
    float srow[2][4][4];
#pragma unroll
    for (int qm = 0; qm < 2; ++qm)
#pragma unroll
        for (int m2 = 0; m2 < 4; ++m2)
#pragma unroll
            for (int r = 0; r < 4; ++r)
                srow[qm][m2][r] = sinv[rowBase + qm * 128 + wr * 64 + m2 * 16 + g * 4 + r];

    // row-direction: rowmax[i] accumulates max_j (s_j * d_ij); s_i applied in finalize
#pragma unroll
    for (int qm = 0; qm < 2; ++qm)
#pragma unroll
        for (int m2 = 0; m2 < 4; ++m2)
#pragma unroll
            for (int r = 0; r < 4; ++r) {
                const int am = qm * 4 + m2;
                const int grow = qm * 128 + wr * 64 + m2 * 16 + g * 4 + r;
                float v = -1e30f;
#pragma unroll
                for (int an = 0; an < 4; ++an) {
                    const int gcol = (an >> 1) * 128 + wc * 32 + (an & 1) * 16 + cl;
                    float f = (float)acc[am][an][r] * scl_col[an];
                    if (diag && grow == gcol) f = -1e30f;   // exclude self-sim
                    v = fmaxf(v, f);
                }
                v = fmaxf(v, __shfl_xor(v, 1));
                v = fmaxf(v, __shfl_xor(v, 2));
                v = fmaxf(v, __shfl_xor(v, 4));
                v = fmaxf(v, __shfl_xor(v, 8));
                if (cl == 0) atomicMax(rowmax + rowBase + grow, fkey(v));
            }

    // col-direction (transpose contribution): max_i (s_i * d_ij); skip on diag
    if (!diag) {
#pragma unroll
        for (int an = 0; an < 4; ++an) {
            float v = -1e30f;
#pragma unroll
            for (int qm = 0; qm < 2; ++qm)
#pragma unroll
                for (int m2 = 0; m2 < 4; ++m2)
#pragma unroll
                    for (int r = 0; r < 4; ++r)
                        v = fmaxf(v, (float)acc[qm * 4 + m2][an][r] * srow[qm][m2][r]);
            v = fmaxf(v, __shfl_xor(v, 16));
            v = fmaxf(v, __shfl_xor(v, 32));
            if (g == 0) {
                const int gcol = colBase + (an >> 1) * 128 + wc * 32 + (an & 1) * 16 + cl;
                atomicMax(rowmax + gcol, fkey(v));
            }
        }
    }
}

__global__ void finalize_kernel(const unsigned* __restrict__ rowmax,
                                const float* __restrict__ sinv,
                                float* __restrict__ out) {
    const int t = threadIdx.x;
    float s = 0.f;
    for (int r = t; r < NROWS; r += 256) {
        const float m = fminf(sinv[r] * funkey(rowmax[r]), 1.0f);   // cos, clamp
        s += logf(2.0f - 2.0f * m + 1e-8f);
    }
#pragma unroll
    for (int off = 32; off > 0; off >>= 1) s += __shfl_xor(s, off);
    __shared__ float ws[4];
    if ((t & 63) == 0) ws[t >> 6] = s;
    __syncthreads();
    if (t == 0) out[0] = -0.5f * (ws[0] + ws[1] + ws[2] + ws[3]) / (float)NROWS;
}

extern "C" void kernel_launch(void* const* d_in, const int* in_sizes, int n_in,
                              void* d_out, int out_size, void* d_ws, size_t ws_size,
                              hipStream_t stream) {
    const float* x = (const float*)d_in[0];
    signed char* xq = (signed char*)d_ws;                                // 16 MB
    float* sinv = (float*)((char*)d_ws + (size_t)NROWS * DIM);           // 64 KB
    unsigned* rowmax = (unsigned*)((char*)d_ws + (size_t)NROWS * DIM + NROWS * sizeof(float));
    float* out = (float*)d_out;

    normalize_rows<<<NROWS, 256, 0, stream>>>(x, xq, sinv, rowmax);
    simmax_kernel<<<NBLK, 512, 0, stream>>>(xq, sinv, rowmax);
    finalize_kernel<<<1, 256, 0, stream>>>(rowmax, sinv, out);
}